// Round 4
// baseline (90.900 us; speedup 1.0000x reference)
//
#include <hip/hip_runtime.h>
#include <math.h>

// Hausdorff distance between binary masks on a 96x96 grid, batch 8, mean.
// Single kernel, 16 blocks (one per sample x direction), no spinning:
//   - phase 1: one pass over the sample loads predict+target, builds the
//     target-set row bitmasks via wave64 ballots AND caches each thread's
//     36 src bits in a register mask (both phases use cell = k*256+tid)
//   - g[r][j] = (nearest set column in row r to j)^2 via ctz/clz on the
//     128-bit row mask (exact, fully parallel)
//   - phase 2: per src cell, scan rows OUTWARD from i with exact early
//     exit (d^2 >= mmin => no farther row can improve); dense random
//     masks exit after ~1-3 rows instead of 96
//   - completion: release-store partial, acq_rel fetch_add on a counter
//     (poison 0xAAAAAAAA => winner sees old == poison+15); last block
//     reduces the 16 partials and writes mean(max(distA,distB)).

#define HH 96
#define WW 96
#define HW 9216
#define GSTR 97               // +1 pad: conflict-free column reads in phase 2
#define NBLK 16               // 8 samples x 2 directions
#define BLK 256
#define KPT (HW / BLK)        // 36 cells per thread
#define SENT 1000
#define SENT2 (SENT * SENT)   // 1e6 >> max real d^2 = 18050
#define POISON 0xAAAAAAAAu

__device__ __forceinline__ int imin(int a, int b) { return a < b ? a : b; }

__device__ __forceinline__ int ctz128(__uint128_t x) {
    unsigned long long lo = (unsigned long long)x;
    unsigned long long hi = (unsigned long long)(x >> 64);
    return lo ? __builtin_ctzll(lo) : 64 + __builtin_ctzll(hi);
}
__device__ __forceinline__ int clz128(__uint128_t x) {
    unsigned long long lo = (unsigned long long)x;
    unsigned long long hi = (unsigned long long)(x >> 64);
    return hi ? __builtin_clzll(hi) : 64 + __builtin_clzll(lo);
}

__global__ __launch_bounds__(BLK) void haus_all(
    const float* __restrict__ predict, const float* __restrict__ target,
    unsigned int* __restrict__ ws, float* __restrict__ out)
{
    __shared__ unsigned long long flat[144]; // 9216 target-set mask bits
    __shared__ int g[HH * GSTR];
    __shared__ float redbuf[BLK / 64];
    __shared__ float part[NBLK];
    __shared__ int winner;

    const int bid  = blockIdx.x;
    const int n    = bid >> 1;         // sample
    const int dir  = bid & 1;          // 0: src=A\B tgt=B ; 1: src=B\A tgt=A
    const int tid  = threadIdx.x;
    const int wave = tid >> 6, lane = tid & 63;

    const float* pbase = predict + n * HW;
    const float* tbase = target  + n * HW;

    // ---- phase 1: one pass builds target bitmask + per-thread src bits ----
    unsigned long long srcmask = 0ULL;
    #pragma unroll 4
    for (int k = 0; k < KPT; ++k) {               // 36 iterations
        int p = k * BLK + tid;
        float pv = pbase[p], tv = tbase[p];
        bool a = pv > 0.5f, b = tv > 0.5f;
        bool tg = dir ? a : b;
        bool sc = dir ? (b && !a) : (a && !b);
        unsigned long long bal = __ballot(tg);
        if (lane == 0) flat[k * 4 + wave] = bal;
        if (sc) srcmask |= 1ULL << k;
    }
    __syncthreads();

    // ---- g[r][j]: squared distance to nearest set column in row r ----
    for (int cell = tid; cell < HW; cell += BLK) {
        int r = cell / WW, j = cell - r * WW;
        int bb = r * 96;                           // row's flat bit offset
        int w0 = bb >> 6;                          // bb&63 is 0 or 32 only
        unsigned long long lo, hi;
        if (bb & 63) {
            lo = (flat[w0] >> 32) | (flat[w0 + 1] << 32);
            hi = flat[w0 + 1] >> 32;               // 32 bits
        } else {
            lo = flat[w0];
            hi = flat[w0 + 1] & 0xFFFFFFFFULL;
        }
        int d;
        if ((lo | hi) == 0ULL) {
            d = SENT;                              // empty row
        } else {
            __uint128_t m = ((__uint128_t)hi << 64) | lo;
            __uint128_t right = m >> j;            // bits at col >= j
            __uint128_t left  = m << (127 - j);    // bit j -> position 127
            int rd = right ? ctz128(right) : SENT;
            int ld = left  ? clz128(left)  : SENT;
            d = imin(rd, ld);
        }
        g[r * GSTR + j] = d * d;
    }
    __syncthreads();

    // ---- phase 2: outward row scan with exact early exit ----
    float local = 0.0f;
    for (int k = 0; k < KPT; ++k) {
        if ((srcmask >> k) & 1) {
            int cell = k * BLK + tid;
            int i = cell / WW, j = cell - i * WW;
            int mmin = g[i * GSTR + j];            // d = 0 (own row)
            for (int d = 1; d < HH; ++d) {
                int dd = d * d;
                if (dd >= mmin) break;             // exact: farther rows >= d^2
                int r0 = i - d, r1 = i + d;
                if (r0 >= 0) mmin = imin(mmin, g[r0 * GSTR + j] + dd);
                if (r1 < HH) mmin = imin(mmin, g[r1 * GSTR + j] + dd);
            }
            float dmin = (mmin < SENT2) ? sqrtf((float)mmin) * (1.0f / 96.0f)
                                        : 1e9f;    // empty target set -> BIG
            local = fmaxf(local, dmin);
        }
    }

    // ---- block max-reduce ----
    for (int off = 32; off; off >>= 1)
        local = fmaxf(local, __shfl_xor(local, off, 64));
    if (lane == 0) redbuf[wave] = local;
    __syncthreads();

    // ---- publish partial; last block (atomic counter chain) finalizes ----
    float* wsf = (float*)ws;                       // ws[0..15]: partials
    if (tid == 0) {
        float mx = fmaxf(fmaxf(redbuf[0], redbuf[1]),
                         fmaxf(redbuf[2], redbuf[3]));
        __hip_atomic_store(&wsf[bid], mx, __ATOMIC_RELEASE,
                           __HIP_MEMORY_SCOPE_AGENT);
        unsigned int old = __hip_atomic_fetch_add(&ws[NBLK], 1u,
                                                  __ATOMIC_ACQ_REL,
                                                  __HIP_MEMORY_SCOPE_AGENT);
        winner = (old == POISON + NBLK - 1) ? 1 : 0;  // poisoned counter
    }
    __syncthreads();

    if (winner && tid < NBLK)
        part[tid] = __hip_atomic_load(&wsf[tid], __ATOMIC_ACQUIRE,
                                      __HIP_MEMORY_SCOPE_AGENT);
    __syncthreads();
    if (winner && tid == 0) {
        float s = 0.0f;
        for (int m = 0; m < 8; ++m)
            s += fmaxf(part[2 * m], part[2 * m + 1]); // max over directions
        out[0] = s * 0.125f;
    }
}

extern "C" void kernel_launch(void* const* d_in, const int* in_sizes, int n_in,
                              void* d_out, int out_size, void* d_ws, size_t ws_size,
                              hipStream_t stream) {
    const float* predict = (const float*)d_in[0];  // [8,1,96,96] f32
    const float* target  = (const float*)d_in[1];  // [8,1,96,96] f32
    float* out = (float*)d_out;                    // scalar f32
    unsigned int* ws = (unsigned int*)d_ws;        // 16 partials + 1 counter

    haus_all<<<dim3(NBLK), dim3(BLK), 0, stream>>>(predict, target, ws, out);
}

// Round 5
// 69.944 us; speedup vs baseline: 1.2996x; 1.2996x over previous
//
#include <hip/hip_runtime.h>
#include <math.h>

// Hausdorff distance between binary masks on a 96x96 grid, batch 8, mean.
// Single kernel, 128 blocks (8 samples x 2 dirs x 8 slices), no spinning.
//   - loads fully decoupled from mask building: 9 independent float4 loads
//     per thread for the target sample (full MLP), nibble per thread into
//     LDS, 144 threads assemble the 96-bit row masks with bit-math (no
//     ballots, no load->crosslane dependency chains)
//   - src-cell operand loads (~5 scalar/thread) issued at kernel entry
//   - g[r][j] = (nearest set column in row r)^2 via ctz/clz on the 128-bit
//     row mask (exact, fully parallel)
//   - phase 2: per src cell, outward row scan with exact early exit
//     (d^2 >= mmin => no farther row can improve)
//   - completion: release-store partial, acq_rel fetch_add on a poisoned
//     counter; last arriving block reduces the 128 partials and writes
//     mean over samples of max(distA, distB).

#define HH 96
#define WW 96
#define HW 9216
#define GSTR 97                 // +1 pad: conflict-free column reads
#define NSLICE 8
#define NBLK (8 * 2 * NSLICE)   // 128 blocks
#define BLK 256
#define CPS (HW / NSLICE)       // 1152 cells per slice
#define SENT 1000
#define SENT2 (SENT * SENT)     // 1e6 >> max real d^2 = 18050
#define POISON 0xAAAAAAAAu

__device__ __forceinline__ int imin(int a, int b) { return a < b ? a : b; }

__device__ __forceinline__ int ctz128(__uint128_t x) {
    unsigned long long lo = (unsigned long long)x;
    unsigned long long hi = (unsigned long long)(x >> 64);
    return lo ? __builtin_ctzll(lo) : 64 + __builtin_ctzll(hi);
}
__device__ __forceinline__ int clz128(__uint128_t x) {
    unsigned long long lo = (unsigned long long)x;
    unsigned long long hi = (unsigned long long)(x >> 64);
    return hi ? __builtin_clzll(hi) : 64 + __builtin_clzll(lo);
}

__global__ __launch_bounds__(BLK) void haus_all(
    const float* __restrict__ predict, const float* __restrict__ target,
    unsigned int* __restrict__ ws, float* __restrict__ out)
{
    __shared__ unsigned long long flat[144];   // 9216 target-set mask bits
    __shared__ unsigned char nib[HW / 4];      // 2304 nibble bytes
    __shared__ int g[HH * GSTR];
    __shared__ float redbuf[BLK / 64];
    __shared__ float part[NBLK];
    __shared__ float hs[8];
    __shared__ int winner;

    const int bid   = blockIdx.x;
    const int n     = bid >> 4;        // sample
    const int dir   = (bid >> 3) & 1;  // 0: src=A\B tgt=B ; 1: src=B\A tgt=A
    const int slice = bid & 7;
    const int tid   = threadIdx.x;
    const int wave  = tid >> 6, lane = tid & 63;

    const float* pbase = predict + n * HW;
    const float* tbase = target  + n * HW;
    const float* tg    = dir ? pbase : tbase;  // target-set array
    const float* other = dir ? tbase : pbase;  // src-side array

    // ---- issue ALL global loads up front (independent -> full MLP) ----
    const int c0 = slice * CPS;
    float ov[5];
    #pragma unroll
    for (int k = 0; k < 4; ++k) ov[k] = other[c0 + k * BLK + tid];
    if (tid < CPS - 4 * BLK) ov[4] = other[c0 + 4 * BLK + tid];

    const float4* tg4 = (const float4*)tg;     // sample base is 16B-aligned
    #pragma unroll
    for (int c = 0; c < 9; ++c) {
        float4 v = tg4[c * BLK + tid];
        unsigned int nb = (unsigned int)(v.x > 0.5f)
                        | ((unsigned int)(v.y > 0.5f) << 1)
                        | ((unsigned int)(v.z > 0.5f) << 2)
                        | ((unsigned int)(v.w > 0.5f) << 3);
        nib[c * BLK + tid] = (unsigned char)nb; // cells 4*(c*256+tid)..+3
    }
    __syncthreads();

    // ---- assemble 64-bit mask words from nibbles (144 threads) ----
    if (tid < 144) {
        const unsigned int* nu = (const unsigned int*)nib;
        unsigned long long w = 0ULL;
        #pragma unroll
        for (int q = 0; q < 4; ++q) {
            unsigned int u = nu[tid * 4 + q] & 0x0F0F0F0Fu;
            u = (u | (u >> 4)) & 0x00FF00FFu;  // pack 4 nibbles -> 16 bits
            u = (u | (u >> 8)) & 0x0000FFFFu;
            w |= (unsigned long long)u << (16 * q);
        }
        flat[tid] = w;
    }

    // ---- src bits for this slice (registers + nibble array) ----
    unsigned int srcmask = 0u;
    #pragma unroll
    for (int k = 0; k < 4; ++k) {
        int cell = c0 + k * BLK + tid;
        int tb = (nib[cell >> 2] >> (cell & 3)) & 1;
        if ((ov[k] > 0.5f) && !tb) srcmask |= 1u << k;
    }
    if (tid < CPS - 4 * BLK) {
        int cell = c0 + 4 * BLK + tid;
        int tb = (nib[cell >> 2] >> (cell & 3)) & 1;
        if ((ov[4] > 0.5f) && !tb) srcmask |= 1u << 4;
    }
    __syncthreads();

    // ---- g[r][j]: squared distance to nearest set column in row r ----
    for (int cell = tid; cell < HW; cell += BLK) {
        int r = cell / WW, j = cell - r * WW;
        int bb = r * 96;                           // row's flat bit offset
        int w0 = bb >> 6;                          // bb&63 is 0 or 32 only
        unsigned long long lo, hi;
        if (bb & 63) {
            lo = (flat[w0] >> 32) | (flat[w0 + 1] << 32);
            hi = flat[w0 + 1] >> 32;               // 32 bits
        } else {
            lo = flat[w0];
            hi = flat[w0 + 1] & 0xFFFFFFFFULL;
        }
        int d;
        if ((lo | hi) == 0ULL) {
            d = SENT;                              // empty row
        } else {
            __uint128_t m = ((__uint128_t)hi << 64) | lo;
            __uint128_t right = m >> j;            // bits at col >= j
            __uint128_t left  = m << (127 - j);    // bit j -> position 127
            int rd = right ? ctz128(right) : SENT;
            int ld = left  ? clz128(left)  : SENT;
            d = imin(rd, ld);
        }
        g[r * GSTR + j] = d * d;
    }
    __syncthreads();

    // ---- phase 2: outward row scan with exact early exit ----
    float local = 0.0f;
    #pragma unroll
    for (int k = 0; k < 5; ++k) {
        if (srcmask & (1u << k)) {                 // k==4 only set for tid<128
            int cell = c0 + k * BLK + tid;
            int i = cell / WW, j = cell - i * WW;
            int mmin = g[i * GSTR + j];            // d = 0 (own row)
            for (int d = 1; d < HH; ++d) {
                int dd = d * d;
                if (dd >= mmin) break;             // exact: farther rows >= d^2
                int r0 = i - d, r1 = i + d;
                if (r0 >= 0)  mmin = imin(mmin, g[r0 * GSTR + j] + dd);
                if (r1 < HH)  mmin = imin(mmin, g[r1 * GSTR + j] + dd);
            }
            float dmin = (mmin < SENT2) ? sqrtf((float)mmin) * (1.0f / 96.0f)
                                        : 1e9f;    // empty target set -> BIG
            local = fmaxf(local, dmin);
        }
    }

    // ---- block max-reduce ----
    for (int off = 32; off; off >>= 1)
        local = fmaxf(local, __shfl_xor(local, off, 64));
    if (lane == 0) redbuf[wave] = local;
    __syncthreads();

    // ---- publish partial; last arriving block finalizes (no spin) ----
    float* wsf = (float*)ws;                       // ws[0..127]: partials
    if (tid == 0) {
        float mx = fmaxf(fmaxf(redbuf[0], redbuf[1]),
                         fmaxf(redbuf[2], redbuf[3]));
        __hip_atomic_store(&wsf[bid], mx, __ATOMIC_RELEASE,
                           __HIP_MEMORY_SCOPE_AGENT);
        unsigned int old = __hip_atomic_fetch_add(&ws[NBLK], 1u,
                                                  __ATOMIC_ACQ_REL,
                                                  __HIP_MEMORY_SCOPE_AGENT);
        winner = (old == POISON + NBLK - 1) ? 1 : 0;  // poisoned counter
    }
    __syncthreads();

    if (winner) {                                  // block-uniform
        if (tid < NBLK)
            part[tid] = __uint_as_float(
                __hip_atomic_load(&ws[tid], __ATOMIC_ACQUIRE,
                                  __HIP_MEMORY_SCOPE_AGENT));
        __syncthreads();
        if (tid < 8) {                             // 16 partials per sample
            float mx = 0.0f;
            for (int k = 0; k < 16; ++k)
                mx = fmaxf(mx, part[tid * 16 + k]);
            hs[tid] = mx;
        }
        __syncthreads();
        if (tid == 0) {
            float s = 0.0f;
            for (int m = 0; m < 8; ++m) s += hs[m];
            out[0] = s * 0.125f;
        }
    }
}

extern "C" void kernel_launch(void* const* d_in, const int* in_sizes, int n_in,
                              void* d_out, int out_size, void* d_ws, size_t ws_size,
                              hipStream_t stream) {
    const float* predict = (const float*)d_in[0];  // [8,1,96,96] f32
    const float* target  = (const float*)d_in[1];  // [8,1,96,96] f32
    float* out = (float*)d_out;                    // scalar f32
    unsigned int* ws = (unsigned int*)d_ws;        // 128 partials + 1 counter

    haus_all<<<dim3(NBLK), dim3(BLK), 0, stream>>>(predict, target, ws, out);
}

// Round 6
// 63.715 us; speedup vs baseline: 1.4267x; 1.0978x over previous
//
#include <hip/hip_runtime.h>
#include <math.h>

// Hausdorff distance between binary masks on a 96x96 grid, batch 8, mean.
// Single kernel, 128 blocks (8 samples x 2 dirs x 8 slices), no spinning.
//   - loads fully decoupled from mask building: 9 independent float4 loads
//     per thread for the target sample (full MLP), nibble per thread into
//     LDS, 144 threads assemble the 96-bit row masks with bit-math
//   - NO g table: phase 2 evaluates the 1D nearest-set-column distance
//     LAZILY per (row, col) query via ctz/clz on the 128-bit row mask.
//     Early-exit outward row scan touches ~5 rows per src cell, so lazy
//     eval is ~8x less work than building the 9216-entry table per block.
//   - completion: release-store partial, acq_rel fetch_add on a poisoned
//     counter; last arriving block reduces the 128 partials and writes
//     mean over samples of max(distA, distB).

#define HH 96
#define WW 96
#define HW 9216
#define NSLICE 8
#define NBLK (8 * 2 * NSLICE)   // 128 blocks
#define BLK 256
#define CPS (HW / NSLICE)       // 1152 cells per slice
#define SENT 1000
#define SENT2 (SENT * SENT)     // 1e6 >> max real d^2 = 18050
#define POISON 0xAAAAAAAAu

__device__ __forceinline__ int imin(int a, int b) { return a < b ? a : b; }

__device__ __forceinline__ int ctz128(__uint128_t x) {
    unsigned long long lo = (unsigned long long)x;
    unsigned long long hi = (unsigned long long)(x >> 64);
    return lo ? __builtin_ctzll(lo) : 64 + __builtin_ctzll(hi);
}
__device__ __forceinline__ int clz128(__uint128_t x) {
    unsigned long long lo = (unsigned long long)x;
    unsigned long long hi = (unsigned long long)(x >> 64);
    return hi ? __builtin_clzll(hi) : 64 + __builtin_clzll(lo);
}

// 1D distance from column j to nearest set column in row r (SENT if empty).
__device__ __forceinline__ int lazy_g(const unsigned long long* __restrict__ flat,
                                      int r, int j) {
    int bb = r * 96;
    int w0 = bb >> 6;                          // bb&63 is 0 or 32 only
    unsigned long long lo, hi;
    if (bb & 63) {
        lo = (flat[w0] >> 32) | (flat[w0 + 1] << 32);
        hi = flat[w0 + 1] >> 32;               // 32 bits
    } else {
        lo = flat[w0];
        hi = flat[w0 + 1] & 0xFFFFFFFFULL;
    }
    if ((lo | hi) == 0ULL) return SENT;        // empty row
    __uint128_t m = ((__uint128_t)hi << 64) | lo;
    __uint128_t right = m >> j;                // bits at col >= j
    __uint128_t left  = m << (127 - j);        // bit j -> position 127
    int rd = right ? ctz128(right) : SENT;
    int ld = left  ? clz128(left)  : SENT;
    return imin(rd, ld);
}

__global__ __launch_bounds__(BLK) void haus_all(
    const float* __restrict__ predict, const float* __restrict__ target,
    unsigned int* __restrict__ ws, float* __restrict__ out)
{
    __shared__ unsigned long long flat[144];   // 9216 target-set mask bits
    __shared__ unsigned char nib[HW / 4];      // 2304 nibble bytes
    __shared__ float redbuf[BLK / 64];
    __shared__ float part[NBLK];
    __shared__ float hs[8];
    __shared__ int winner;

    const int bid   = blockIdx.x;
    const int n     = bid >> 4;        // sample
    const int dir   = (bid >> 3) & 1;  // 0: src=A\B tgt=B ; 1: src=B\A tgt=A
    const int slice = bid & 7;
    const int tid   = threadIdx.x;
    const int wave  = tid >> 6, lane = tid & 63;

    const float* pbase = predict + n * HW;
    const float* tbase = target  + n * HW;
    const float* tg    = dir ? pbase : tbase;  // target-set array
    const float* other = dir ? tbase : pbase;  // src-side array

    // ---- issue ALL global loads up front (independent -> full MLP) ----
    const int c0 = slice * CPS;
    float ov[5];
    #pragma unroll
    for (int k = 0; k < 4; ++k) ov[k] = other[c0 + k * BLK + tid];
    if (tid < CPS - 4 * BLK) ov[4] = other[c0 + 4 * BLK + tid];

    const float4* tg4 = (const float4*)tg;     // sample base is 16B-aligned
    #pragma unroll
    for (int c = 0; c < 9; ++c) {
        float4 v = tg4[c * BLK + tid];
        unsigned int nb = (unsigned int)(v.x > 0.5f)
                        | ((unsigned int)(v.y > 0.5f) << 1)
                        | ((unsigned int)(v.z > 0.5f) << 2)
                        | ((unsigned int)(v.w > 0.5f) << 3);
        nib[c * BLK + tid] = (unsigned char)nb; // cells 4*(c*256+tid)..+3
    }
    __syncthreads();

    // ---- assemble 64-bit mask words from nibbles (144 threads) ----
    if (tid < 144) {
        const unsigned int* nu = (const unsigned int*)nib;
        unsigned long long w = 0ULL;
        #pragma unroll
        for (int q = 0; q < 4; ++q) {
            unsigned int u = nu[tid * 4 + q] & 0x0F0F0F0Fu;
            u = (u | (u >> 4)) & 0x00FF00FFu;  // pack 4 nibbles -> 16 bits
            u = (u | (u >> 8)) & 0x0000FFFFu;
            w |= (unsigned long long)u << (16 * q);
        }
        flat[tid] = w;
    }

    // ---- src bits for this slice (registers + nibble array) ----
    unsigned int srcmask = 0u;
    #pragma unroll
    for (int k = 0; k < 4; ++k) {
        int cell = c0 + k * BLK + tid;
        int tb = (nib[cell >> 2] >> (cell & 3)) & 1;
        if ((ov[k] > 0.5f) && !tb) srcmask |= 1u << k;
    }
    if (tid < CPS - 4 * BLK) {
        int cell = c0 + 4 * BLK + tid;
        int tb = (nib[cell >> 2] >> (cell & 3)) & 1;
        if ((ov[4] > 0.5f) && !tb) srcmask |= 1u << 4;
    }
    __syncthreads();

    // ---- phase 2: outward row scan, lazy g eval, exact early exit ----
    float local = 0.0f;
    #pragma unroll
    for (int k = 0; k < 5; ++k) {
        if (srcmask & (1u << k)) {             // k==4 only set for tid<128
            int cell = c0 + k * BLK + tid;
            int i = cell / WW, j = cell - i * WW;
            int e0 = lazy_g(flat, i, j);       // own row (d = 0)
            int mmin = e0 * e0;
            for (int d = 1; d < HH; ++d) {
                int dd = d * d;
                if (dd >= mmin) break;         // exact: farther rows >= d^2
                int r0 = i - d, r1 = i + d;
                if (r0 >= 0) {
                    int e = lazy_g(flat, r0, j);
                    mmin = imin(mmin, e * e + dd);
                }
                if (r1 < HH) {
                    int e = lazy_g(flat, r1, j);
                    mmin = imin(mmin, e * e + dd);
                }
            }
            float dmin = (mmin < SENT2) ? sqrtf((float)mmin) * (1.0f / 96.0f)
                                        : 1e9f; // empty target set -> BIG
            local = fmaxf(local, dmin);
        }
    }

    // ---- block max-reduce ----
    for (int off = 32; off; off >>= 1)
        local = fmaxf(local, __shfl_xor(local, off, 64));
    if (lane == 0) redbuf[wave] = local;
    __syncthreads();

    // ---- publish partial; last arriving block finalizes (no spin) ----
    float* wsf = (float*)ws;                   // ws[0..127]: partials
    if (tid == 0) {
        float mx = fmaxf(fmaxf(redbuf[0], redbuf[1]),
                         fmaxf(redbuf[2], redbuf[3]));
        __hip_atomic_store(&wsf[bid], mx, __ATOMIC_RELEASE,
                           __HIP_MEMORY_SCOPE_AGENT);
        unsigned int old = __hip_atomic_fetch_add(&ws[NBLK], 1u,
                                                  __ATOMIC_ACQ_REL,
                                                  __HIP_MEMORY_SCOPE_AGENT);
        winner = (old == POISON + NBLK - 1) ? 1 : 0;  // poisoned counter
    }
    __syncthreads();

    if (winner) {                              // block-uniform
        if (tid < NBLK)
            part[tid] = __uint_as_float(
                __hip_atomic_load(&ws[tid], __ATOMIC_ACQUIRE,
                                  __HIP_MEMORY_SCOPE_AGENT));
        __syncthreads();
        if (tid < 8) {                         // 16 partials per sample
            float mx = 0.0f;
            for (int k = 0; k < 16; ++k)
                mx = fmaxf(mx, part[tid * 16 + k]);
            hs[tid] = mx;
        }
        __syncthreads();
        if (tid == 0) {
            float s = 0.0f;
            for (int m = 0; m < 8; ++m) s += hs[m];
            out[0] = s * 0.125f;
        }
    }
}

extern "C" void kernel_launch(void* const* d_in, const int* in_sizes, int n_in,
                              void* d_out, int out_size, void* d_ws, size_t ws_size,
                              hipStream_t stream) {
    const float* predict = (const float*)d_in[0];  // [8,1,96,96] f32
    const float* target  = (const float*)d_in[1];  // [8,1,96,96] f32
    float* out = (float*)d_out;                    // scalar f32
    unsigned int* ws = (unsigned int*)d_ws;        // 128 partials + 1 counter

    haus_all<<<dim3(NBLK), dim3(BLK), 0, stream>>>(predict, target, ws, out);
}